// Round 5
// baseline (979.621 us; speedup 1.0000x reference)
//
#include <hip/hip_runtime.h>
#include <hip/hip_bf16.h>
#include <math.h>

#define L_ 37
#define K_ 8
#define HM_ 512
#define HS_ 128
#define HC_ 64

using f32x4 = __attribute__((ext_vector_type(4))) float;
typedef int i32x8 __attribute__((ext_vector_type(8)));

// ---- conv LDS geometry ----
// L: 128 rows x 256B (64B zero front, 128B data, 64B zero tail). P: 160 rows x 128B
// (rows 0..15,144..159 zero; data rows 16..143), 16B-chunk XOR swizzle by (row&7).
#define PB_OFF   32768
#define CONV_LDS (PB_OFF + 160*128)   // 53248 -> 3 blocks/CU

// ---- ws layout (bytes) ----
static constexpr size_t OFF_SUMS   = 0;
static constexpr size_t OFF_PARAMS = 512;
static constexpr size_t OFF_TAJ    = 1024;
static constexpr size_t OFF_TAW    = 1536;
static constexpr size_t OFF_TBJ    = 9728;
static constexpr size_t OFF_TBW    = 10240;
static constexpr size_t OFF_TCJ    = 12288;
static constexpr size_t OFF_TCW    = 14336;
static constexpr size_t OFF_PART   = 22528;
static constexpr size_t OFF_HMRS   = 32768;                                // 74*16384 f
static constexpr size_t OFF_PIMG   = OFF_HMRS + (size_t)74*16384*4;        // 296*16384 u8
static constexpr size_t OFF_E128   = OFF_PIMG + (size_t)296*16384;         // 74*16384 f

__device__ __forceinline__ float keys_cubic(float x) {
  float out = ((1.5f * x - 2.5f) * x) * x + 1.f;
  if (x >= 1.f) out = ((-0.5f * x + 2.5f) * x - 4.f) * x + 2.f;
  if (x >= 2.f) out = 0.f;
  return out;
}
__device__ __forceinline__ float sp(float x) {
  float z = 5.f * x;
  return (fmaxf(z, 0.f) + log1pf(expf(-fabsf(z)))) * 0.2f;
}

// ---------------- BN partial sums ----------------
__global__ void bn_partial_k(const float* __restrict__ heat, float* __restrict__ sums) {
  int l = blockIdx.x >> 4, seg = blockIdx.x & 15;
  int tid = threadIdx.x;
  float s = 0.f, q = 0.f;
  for (int i = tid; i < 8192; i += 256) {
    int f4 = seg * 8192 + i;
    int b = f4 >> 16, rem = f4 & 65535;
    float4 v = ((const float4*)heat)[(size_t)(b * L_ + l) * 65536 + rem];
    s += v.x + v.y + v.z + v.w;
    q += v.x*v.x + v.y*v.y + v.z*v.z + v.w*v.w;
  }
  __shared__ float rs[256], rq[256];
  rs[tid] = s; rq[tid] = q; __syncthreads();
  for (int o = 128; o > 0; o >>= 1) {
    if (tid < o) { rs[tid] += rs[tid + o]; rq[tid] += rq[tid + o]; }
    __syncthreads();
  }
  if (tid == 0) { atomicAdd(&sums[2*l], rs[0]); atomicAdd(&sums[2*l+1], rq[0]); }
}

// ---------------- tables + BN params ----------------
__global__ void tables_k(int* taj, float* taw, int* tbj, float* tbw, int* tcj, float* tcw,
                         const float* __restrict__ sums, const float* __restrict__ gamma,
                         const float* __restrict__ beta, float* __restrict__ params) {
  int i = threadIdx.x;
  if (i < 128) {
    float sf = 4.f * i + 1.5f;
    int j0 = 4 * i - 6;
    taj[i] = j0;
    float w[16], sum = 0.f;
    for (int t = 0; t < 16; ++t) {
      int j = j0 + t; float ww = 0.f;
      if (j >= 0 && j < 512) ww = keys_cubic(fabsf(sf - (float)j) * 0.25f);
      w[t] = ww; sum += ww;
    }
    for (int t = 0; t < 16; ++t) taw[i*16 + t] = w[t] / sum;
    float sb = 0.5f * i - 0.25f;
    int jb = (int)floorf(sb) - 1;
    tbj[i] = jb;
    float wb[4], sumb = 0.f;
    for (int t = 0; t < 4; ++t) {
      int j = jb + t; float ww = 0.f;
      if (j >= 0 && j < 64) ww = keys_cubic(fabsf(sb - (float)j));
      wb[t] = ww; sumb += ww;
    }
    for (int t = 0; t < 4; ++t) tbw[i*4 + t] = wb[t] / sumb;
  }
  if (i < 512) {
    float sc = 0.25f * i - 0.375f;
    int jc = (int)floorf(sc) - 1;
    tcj[i] = jc;
    float wc[4], sumc = 0.f;
    for (int t = 0; t < 4; ++t) {
      int j = jc + t; float ww = 0.f;
      if (j >= 0 && j < 128) ww = keys_cubic(fabsf(sc - (float)j));
      wc[t] = ww; sumc += ww;
    }
    for (int t = 0; t < 4; ++t) tcw[i*4 + t] = wc[t] / sumc;
  }
  if (i < L_) {
    float inv = 1.f / (2.f * HM_ * HM_);
    float mean = sums[2*i] * inv;
    float var  = sums[2*i+1] * inv - mean * mean;
    float sc = gamma[i] * rsqrtf(var + 1e-5f);
    params[2*i] = sc;
    params[2*i+1] = beta[i] - mean * sc;
  }
}

// ---------------- fused downsample (no BN; resize is affine-exact) ----------------
// block = (bl, group of 4 output rows). Stage 28 input rows in LDS, 2-stage bicubic.
__global__ __launch_bounds__(256) void down_fused_k(
    const float* __restrict__ heat, const int* __restrict__ taj,
    const float* __restrict__ taw, float* __restrict__ hmrs) {
  extern __shared__ float sds[];
  float* in = sds;           // [28][512]
  float* rm = sds + 28*512;  // [4][512]
  int bl = blockIdx.x >> 5, ig = blockIdx.x & 31;
  int i0 = ig * 4;
  int j00 = 4*i0 - 6;
  int tid = threadIdx.x;
  const float* hb = heat + (size_t)bl * 262144;
  for (int idx = tid; idx < 28*128; idx += 256) {
    int jr = idx >> 7, c4 = (idx & 127) << 2;
    int j = min(511, max(0, j00 + jr));
    *(float4*)(in + jr*512 + c4) = *(const float4*)(hb + (size_t)j*512 + c4);
  }
  __syncthreads();
  for (int idx = tid; idx < 2048; idx += 256) {
    int ri = idx >> 9, c = idx & 511;
    const float* wt = taw + (i0 + ri) * 16;
    float a = 0.f;
    #pragma unroll
    for (int t = 0; t < 16; ++t) a = fmaf(wt[t], in[(4*ri + t)*512 + c], a);
    rm[ri*512 + c] = a;
  }
  __syncthreads();
  for (int idx = tid; idx < 512; idx += 256) {
    int ri = idx >> 7, ic = idx & 127;
    int j0 = taj[ic];
    float a = 0.f;
    #pragma unroll
    for (int t = 0; t < 16; ++t) {
      int j = min(511, max(0, j0 + t));
      a = fmaf(taw[ic*16 + t], rm[ri*512 + j], a);
    }
    hmrs[((size_t)bl*128 + i0 + ri)*128 + ic] = a;
  }
}

// ---------------- prior: sp(upsample(cond)) -> reversed fp8, 16B-chunk swizzled ----------------
// Prev[s][jj] = P[s][127-jj]; logical 16B chunk c16 stored at (c16 ^ (s&7)).
__global__ void prior_rev_k(const float* __restrict__ cond, const int* __restrict__ tbj,
                            const float* __restrict__ tbw, unsigned char* __restrict__ pimg) {
  __shared__ float c64[HC_*HC_];
  int lk = blockIdx.x;
  const float* src = cond + (size_t)lk * HC_*HC_;
  for (int i = threadIdx.x; i < HC_*HC_; i += 256) c64[i] = src[i];
  __syncthreads();
  for (int t = threadIdx.x; t < 1024; t += 256) {
    int s = t >> 3, c16 = t & 7;
    int jy0 = tbj[s];
    float wy[4]; int jys[4];
    #pragma unroll
    for (int q = 0; q < 4; ++q) { wy[q] = tbw[s*4+q]; jys[q] = min(63, max(0, jy0 + q)); }
    unsigned w[4];
    #pragma unroll
    for (int q = 0; q < 4; ++q) {
      float vv[4];
      #pragma unroll
      for (int bq = 0; bq < 4; ++bq) {
        int jj = 16*c16 + 4*q + bq;
        int j = 127 - jj;
        int jx0 = tbj[j];
        float acc = 0.f;
        #pragma unroll
        for (int ty = 0; ty < 4; ++ty) {
          float r = 0.f;
          #pragma unroll
          for (int tx = 0; tx < 4; ++tx) {
            int jx = min(63, max(0, jx0 + tx));
            r = fmaf(tbw[j*4 + tx], c64[jys[ty]*64 + jx], r);
          }
          acc = fmaf(wy[ty], r, acc);
        }
        vv[bq] = sp(acc);
      }
      int wq = 0;
      wq = __builtin_amdgcn_cvt_pk_fp8_f32(vv[0], vv[1], wq, false);
      wq = __builtin_amdgcn_cvt_pk_fp8_f32(vv[2], vv[3], wq, true);
      w[q] = (unsigned)wq;
    }
    unsigned char* dst = pimg + (size_t)lk*16384 + s*128 + ((c16 ^ (s & 7)) << 4);
    *(uint4*)dst = make_uint4(w[0], w[1], w[2], w[3]);
  }
}

// ---------------- conv: implicit-Toeplitz MX-fp8 K=128 MFMA ----------------
// out[y][x] = sum_u sum_k Prev[y+64-u][k] * L[u][x-63+k]   (k = 127-t)
// A[m][k]: m=lane&15, k=32*kg+j  -> 32B swizzled P row read (2x b128)
// B[k][n]: n=lane&15, k=32*kg+j  -> byte window, shared 21-dword load across 4 nt
__global__ __launch_bounds__(256, 3) void conv_mfma_k(
    const float* __restrict__ hmrs, const unsigned char* __restrict__ pimg,
    const float* __restrict__ bias, const int* __restrict__ vidx,
    const float* __restrict__ params, float* __restrict__ e128) {
  extern __shared__ char lds[];
  char* Lb = lds;
  char* Pb = lds + PB_OFF;
  int blk = blockIdx.x;
  int b = blk / 296, lk = blk % 296, l = lk >> 3;
  int tid = threadIdx.x;

  // zero L pads: per row dwords 0..15 and 48..63
  {
    unsigned* lz = (unsigned*)Lb;
    for (int i = tid; i < 4096; i += 256) {
      int row = i >> 5, q = i & 31;
      lz[row*64 + (q < 16 ? q : q + 32)] = 0u;
    }
  }
  // zero P pad rows 0..15, 144..159
  {
    unsigned* pz = (unsigned*)Pb;
    for (int i = tid; i < 1024; i += 256) {
      int row = i >> 5;
      pz[(row < 16 ? row : row + 128)*32 + (i & 31)] = 0u;
    }
  }
  // stage L = fp8(sp(sc*hmrs+sh))
  int vl = vidx[lk];
  float sc = params[2*vl], sh = params[2*vl + 1];
  const float4* likes4 = (const float4*)(hmrs + (size_t)(b * L_ + vl) * 16384);
  for (int i = tid; i < 1024; i += 256) {
    int u = i >> 3, ch = i & 7;
    int b4 = u * 32 + ch * 4;
    unsigned wds[4];
    #pragma unroll
    for (int q = 0; q < 4; ++q) {
      float4 v = likes4[b4 + q];
      int w = 0;
      w = __builtin_amdgcn_cvt_pk_fp8_f32(sp(fmaf(v.x, sc, sh)), sp(fmaf(v.y, sc, sh)), w, false);
      w = __builtin_amdgcn_cvt_pk_fp8_f32(sp(fmaf(v.z, sc, sh)), sp(fmaf(v.w, sc, sh)), w, true);
      wds[q] = (unsigned)w;
    }
    *(uint4*)(Lb + u*256 + 64 + ch*16) = make_uint4(wds[0], wds[1], wds[2], wds[3]);
  }
  // stage P data rows 16..143 (pre-swizzled)
  {
    const uint4* src = (const uint4*)(pimg + (size_t)lk * 16384);
    uint4* dst = (uint4*)(Pb + 16*128);
    for (int i = tid; i < 1024; i += 256) dst[i] = src[i];
  }
  __syncthreads();

  int wid = tid >> 6, lane = tid & 63;
  int wm = wid >> 1, wn = wid & 1;
  int l15 = lane & 15, kg = lane >> 4;
  int x0 = wn * 64, y_base = wm * 64;
  int bb = 1 + x0 + l15 + 32*kg;
  int bd0 = bb >> 2;
  int shiftB = (bb & 3) * 8;

  f32x4 acc[4][4];
  #pragma unroll
  for (int mt = 0; mt < 4; ++mt)
    #pragma unroll
    for (int nt = 0; nt < 4; ++nt)
      #pragma unroll
      for (int j = 0; j < 4; ++j) acc[mt][nt][j] = 0.f;

  int u_lo = wm ? 1 : 0;
  #pragma unroll 1
  for (int u = u_lo; u < 128; ++u) {
    const unsigned* Lr = (const unsigned*)(Lb + (u << 8));
    unsigned d[21];
    #pragma unroll
    for (int q = 0; q < 21; ++q) d[q] = Lr[bd0 + q];
    i32x8 Bf[4];
    #pragma unroll
    for (int nt = 0; nt < 4; ++nt)
      #pragma unroll
      for (int j = 0; j < 8; ++j)
        Bf[nt][j] = (int)(unsigned)((((unsigned long long)d[4*nt + j + 1] << 32) | d[4*nt + j]) >> shiftB);
    #pragma unroll
    for (int mt = 0; mt < 4; ++mt) {
      int yt = y_base + 16*mt;
      if (u < yt - 63 || u > yt + 79) continue;
      int r = yt + l15 + 80 - u;                       // storage row 1..158
      const char* pr = Pb + (r << 7);
      int m8 = r & 7;
      uint4 alo = *(const uint4*)(pr + (((2*kg)     ^ m8) << 4));
      uint4 ahi = *(const uint4*)(pr + (((2*kg + 1) ^ m8) << 4));
      i32x8 Af;
      Af[0] = (int)alo.x; Af[1] = (int)alo.y; Af[2] = (int)alo.z; Af[3] = (int)alo.w;
      Af[4] = (int)ahi.x; Af[5] = (int)ahi.y; Af[6] = (int)ahi.z; Af[7] = (int)ahi.w;
      #pragma unroll
      for (int nt = 0; nt < 4; ++nt)
        acc[mt][nt] = __builtin_amdgcn_mfma_scale_f32_16x16x128_f8f6f4(
            Af, Bf[nt], acc[mt][nt], 0, 0, 0, 0x7F7F7F7F, 0, 0x7F7F7F7F);
    }
  }

  // epilogue: atomic log-energy accumulation over k
  const float* bs = bias + (size_t)lk * 16384;
  float* e = e128 + (size_t)(b * L_ + l) * 16384;
  #pragma unroll
  for (int mt = 0; mt < 4; ++mt)
    #pragma unroll
    for (int nt = 0; nt < 4; ++nt) {
      int x = x0 + nt*16 + l15;
      int yb = y_base + mt*16 + kg*4;
      #pragma unroll
      for (int rg = 0; rg < 4; ++rg) {
        int y = yb + rg;
        float v = acc[mt][nt][rg] + sp(bs[y*128 + x]) + 1e-6f;
        atomicAdd(&e[y*128 + x], logf(v));
      }
    }
}

// ---------------- final: premixed bicubic upsample + online softmax partials ----------------
__global__ __launch_bounds__(256) void final_partial_k(
    const float* __restrict__ heat, const float* __restrict__ params,
    const float* __restrict__ e128, const int* __restrict__ tcj, const float* __restrict__ tcw,
    float* __restrict__ partials) {
  __shared__ float Elds[20 * 128];
  __shared__ float Eh[20 * 512];
  __shared__ float rm[256], rS[256], ry[256], rx[256];
  int blk = blockIdx.x;
  int bl = blk >> 3, seg = blk & 7;
  int l = bl % L_;
  int tid = threadIdx.x;
  float sc = params[2*l], sh = params[2*l+1];
  int y_lo = seg * 64;
  int r_lo = max(0, tcj[y_lo]);
  int r_hi = min(127, tcj[y_lo + 63] + 3);
  int nrows = r_hi - r_lo + 1;
  const float* E = e128 + (size_t)bl * 16384;
  for (int i = tid; i < nrows * 128; i += 256) Elds[i] = E[r_lo * 128 + i];
  __syncthreads();
  // horizontal premix: Eh[r][x] = sum_tx wx * Elds[r][jx]
  for (int idx = tid; idx < (nrows << 9); idx += 256) {
    int r = idx >> 9, x = idx & 511;
    int j0 = tcj[x];
    float a = 0.f;
    #pragma unroll
    for (int t = 0; t < 4; ++t) {
      int j = min(127, max(0, j0 + t));
      a = fmaf(tcw[x*4 + t], Elds[r*128 + j], a);
    }
    Eh[r*512 + x] = a;
  }
  __syncthreads();

  float m = -1e30f, S = 0.f, Sy = 0.f, Sx = 0.f;
  for (int y = y_lo; y < y_lo + 64; ++y) {
    int jy0 = tcj[y];
    float wy[4]; int jyr[4];
    #pragma unroll
    for (int t = 0; t < 4; ++t) { wy[t] = tcw[y*4 + t]; jyr[t] = min(127, max(0, jy0 + t)) - r_lo; }
    #pragma unroll
    for (int xi = 0; xi < 2; ++xi) {
      int x = tid + xi * 256;
      float a = wy[0]*Eh[jyr[0]*512 + x] + wy[1]*Eh[jyr[1]*512 + x]
              + wy[2]*Eh[jyr[2]*512 + x] + wy[3]*Eh[jyr[3]*512 + x];
      float hm = fmaf(heat[(size_t)bl * 262144 + y * 512 + x], sc, sh);
      float e = a + logf(sp(hm) + 1e-6f);
      if (e > m) {
        float f = expf(m - e);
        S *= f; Sy *= f; Sx *= f; m = e;
      }
      float w = expf(e - m);
      S += w; Sy = fmaf(w, (float)y, Sy); Sx = fmaf(w, (float)x, Sx);
    }
  }
  rm[tid] = m; rS[tid] = S; ry[tid] = Sy; rx[tid] = Sx; __syncthreads();
  for (int o = 128; o > 0; o >>= 1) {
    if (tid < o) {
      float ma = rm[tid], mb = rm[tid + o];
      float M = fmaxf(ma, mb);
      float fa = expf(ma - M), fb = expf(mb - M);
      rS[tid] = rS[tid]*fa + rS[tid+o]*fb;
      ry[tid] = ry[tid]*fa + ry[tid+o]*fb;
      rx[tid] = rx[tid]*fa + rx[tid+o]*fb;
      rm[tid] = M;
    }
    __syncthreads();
  }
  if (tid == 0) {
    float* p = partials + (size_t)blk * 4;
    p[0] = rm[0]; p[1] = rS[0]; p[2] = ry[0]; p[3] = rx[0];
  }
}

__global__ void final_combine_k(const float* __restrict__ partials, float* __restrict__ out) {
  int bl = blockIdx.x;
  if (threadIdx.x != 0) return;
  float M = -1e30f, S = 0.f, Sy = 0.f, Sx = 0.f;
  for (int i = 0; i < 8; ++i) {
    const float* p = partials + (size_t)(bl * 8 + i) * 4;
    float m2 = p[0], s2 = p[1], sy2 = p[2], sx2 = p[3];
    float Mn = fmaxf(M, m2);
    float fa = expf(M - Mn), fb = expf(m2 - Mn);
    S = S*fa + s2*fb; Sy = Sy*fa + sy2*fb; Sx = Sx*fa + sx2*fb; M = Mn;
  }
  out[bl*3 + 0] = 1.f;
  out[bl*3 + 1] = Sy / S;
  out[bl*3 + 2] = Sx / S;
}

extern "C" void kernel_launch(void* const* d_in, const int* in_sizes, int n_in,
                              void* d_out, int out_size, void* d_ws, size_t ws_size,
                              hipStream_t stream) {
  const float* heat  = (const float*)d_in[0];
  const float* cond  = (const float*)d_in[1];
  const float* bias  = (const float*)d_in[2];
  const float* gamma = (const float*)d_in[3];
  const float* beta  = (const float*)d_in[4];
  const int*   vidx  = (const int*)d_in[5];
  float* out = (float*)d_out;
  char* ws = (char*)d_ws;

  float* sums   = (float*)(ws + OFF_SUMS);
  float* params = (float*)(ws + OFF_PARAMS);
  int*   taj = (int*)(ws + OFF_TAJ);   float* taw = (float*)(ws + OFF_TAW);
  int*   tbj = (int*)(ws + OFF_TBJ);   float* tbw = (float*)(ws + OFF_TBW);
  int*   tcj = (int*)(ws + OFF_TCJ);   float* tcw = (float*)(ws + OFF_TCW);
  float* part  = (float*)(ws + OFF_PART);
  float* hmrs  = (float*)(ws + OFF_HMRS);
  unsigned char* pimg = (unsigned char*)(ws + OFF_PIMG);
  float* e128  = (float*)(ws + OFF_E128);

  hipFuncSetAttribute((const void*)conv_mfma_k,
                      hipFuncAttributeMaxDynamicSharedMemorySize, CONV_LDS);
  hipFuncSetAttribute((const void*)down_fused_k,
                      hipFuncAttributeMaxDynamicSharedMemorySize, 32*512*4);

  hipMemsetAsync(sums, 0, 2 * L_ * sizeof(float), stream);
  hipMemsetAsync(e128, 0, (size_t)74 * 16384 * 4, stream);

  bn_partial_k<<<L_ * 16, 256, 0, stream>>>(heat, sums);
  tables_k<<<1, 512, 0, stream>>>(taj, taw, tbj, tbw, tcj, tcw, sums, gamma, beta, params);
  down_fused_k<<<74 * 32, 256, 32*512*4, stream>>>(heat, taj, taw, hmrs);
  prior_rev_k<<<L_ * K_, 256, 0, stream>>>(cond, tbj, tbw, pimg);
  conv_mfma_k<<<2 * L_ * K_, 256, CONV_LDS, stream>>>(hmrs, pimg, bias, vidx, params, e128);
  final_partial_k<<<74 * 8, 256, 0, stream>>>(heat, params, e128, tcj, tcw, part);
  final_combine_k<<<74, 64, 0, stream>>>(part, out);
}

// Round 6
// 867.593 us; speedup vs baseline: 1.1291x; 1.1291x over previous
//
#include <hip/hip_runtime.h>
#include <hip/hip_bf16.h>
#include <math.h>

#define L_ 37
#define K_ 8
#define HM_ 512
#define HS_ 128
#define HC_ 64

using f32x4 = __attribute__((ext_vector_type(4))) float;
typedef int i32x8 __attribute__((ext_vector_type(8)));

// ---- conv LDS geometry ----
// L: 128 rows x 256B (64B zero front, 128B data, 64B zero tail). P: 160 rows x 128B
// (rows 0..15,144..159 zero; data rows 16..143), 16B-chunk XOR swizzle by (row&7).
#define PB_OFF   32768
#define CONV_LDS (PB_OFF + 160*128)   // 53248 -> 3 blocks/CU

// ---- ws layout (bytes) ----
static constexpr size_t OFF_SUMS   = 0;
static constexpr size_t OFF_PARAMS = 512;
static constexpr size_t OFF_TAJ    = 1024;
static constexpr size_t OFF_TAW    = 1536;
static constexpr size_t OFF_TBJ    = 9728;
static constexpr size_t OFF_TBW    = 10240;
static constexpr size_t OFF_TCJ    = 12288;
static constexpr size_t OFF_TCW    = 14336;
static constexpr size_t OFF_PART   = 22528;
static constexpr size_t OFF_HMRS   = 32768;                                // 74*16384 f
static constexpr size_t OFF_PIMG   = OFF_HMRS + (size_t)74*16384*4;        // 296*16384 u8
static constexpr size_t OFF_EALL   = OFF_PIMG + (size_t)296*16384;         // 592*16384 f
static constexpr size_t OFF_E128   = OFF_EALL + (size_t)592*16384*4;       // 74*16384 f

__device__ __forceinline__ float keys_cubic(float x) {
  float out = ((1.5f * x - 2.5f) * x) * x + 1.f;
  if (x >= 1.f) out = ((-0.5f * x + 2.5f) * x - 4.f) * x + 2.f;
  if (x >= 2.f) out = 0.f;
  return out;
}
__device__ __forceinline__ float sp(float x) {
  float z = 5.f * x;
  return (fmaxf(z, 0.f) + log1pf(expf(-fabsf(z)))) * 0.2f;
}

// ---------------- BN partial sums ----------------
__global__ void bn_partial_k(const float* __restrict__ heat, float* __restrict__ sums) {
  int l = blockIdx.x >> 4, seg = blockIdx.x & 15;
  int tid = threadIdx.x;
  float s = 0.f, q = 0.f;
  for (int i = tid; i < 8192; i += 256) {
    int f4 = seg * 8192 + i;
    int b = f4 >> 16, rem = f4 & 65535;
    float4 v = ((const float4*)heat)[(size_t)(b * L_ + l) * 65536 + rem];
    s += v.x + v.y + v.z + v.w;
    q += v.x*v.x + v.y*v.y + v.z*v.z + v.w*v.w;
  }
  __shared__ float rs[256], rq[256];
  rs[tid] = s; rq[tid] = q; __syncthreads();
  for (int o = 128; o > 0; o >>= 1) {
    if (tid < o) { rs[tid] += rs[tid + o]; rq[tid] += rq[tid + o]; }
    __syncthreads();
  }
  if (tid == 0) { atomicAdd(&sums[2*l], rs[0]); atomicAdd(&sums[2*l+1], rq[0]); }
}

// ---------------- tables + BN params ----------------
__global__ void tables_k(int* taj, float* taw, int* tbj, float* tbw, int* tcj, float* tcw,
                         const float* __restrict__ sums, const float* __restrict__ gamma,
                         const float* __restrict__ beta, float* __restrict__ params) {
  int i = threadIdx.x;
  if (i < 128) {
    float sf = 4.f * i + 1.5f;
    int j0 = 4 * i - 6;
    taj[i] = j0;
    float w[16], sum = 0.f;
    for (int t = 0; t < 16; ++t) {
      int j = j0 + t; float ww = 0.f;
      if (j >= 0 && j < 512) ww = keys_cubic(fabsf(sf - (float)j) * 0.25f);
      w[t] = ww; sum += ww;
    }
    for (int t = 0; t < 16; ++t) taw[i*16 + t] = w[t] / sum;
    float sb = 0.5f * i - 0.25f;
    int jb = (int)floorf(sb) - 1;
    tbj[i] = jb;
    float wb[4], sumb = 0.f;
    for (int t = 0; t < 4; ++t) {
      int j = jb + t; float ww = 0.f;
      if (j >= 0 && j < 64) ww = keys_cubic(fabsf(sb - (float)j));
      wb[t] = ww; sumb += ww;
    }
    for (int t = 0; t < 4; ++t) tbw[i*4 + t] = wb[t] / sumb;
  }
  if (i < 512) {
    float sc = 0.25f * i - 0.375f;
    int jc = (int)floorf(sc) - 1;
    tcj[i] = jc;
    float wc[4], sumc = 0.f;
    for (int t = 0; t < 4; ++t) {
      int j = jc + t; float ww = 0.f;
      if (j >= 0 && j < 128) ww = keys_cubic(fabsf(sc - (float)j));
      wc[t] = ww; sumc += ww;
    }
    for (int t = 0; t < 4; ++t) tcw[i*4 + t] = wc[t] / sumc;
  }
  if (i < L_) {
    float inv = 1.f / (2.f * HM_ * HM_);
    float mean = sums[2*i] * inv;
    float var  = sums[2*i+1] * inv - mean * mean;
    float sc = gamma[i] * rsqrtf(var + 1e-5f);
    params[2*i] = sc;
    params[2*i+1] = beta[i] - mean * sc;
  }
}

// ---------------- fused downsample (no BN; resize is affine-exact) ----------------
__global__ __launch_bounds__(256) void down_fused_k(
    const float* __restrict__ heat, const int* __restrict__ taj,
    const float* __restrict__ taw, float* __restrict__ hmrs) {
  extern __shared__ float sds[];
  float* in = sds;           // [28][512]
  float* rm = sds + 28*512;  // [4][512]
  int bl = blockIdx.x >> 5, ig = blockIdx.x & 31;
  int i0 = ig * 4;
  int j00 = 4*i0 - 6;
  int tid = threadIdx.x;
  const float* hb = heat + (size_t)bl * 262144;
  for (int idx = tid; idx < 28*128; idx += 256) {
    int jr = idx >> 7, c4 = (idx & 127) << 2;
    int j = min(511, max(0, j00 + jr));
    *(float4*)(in + jr*512 + c4) = *(const float4*)(hb + (size_t)j*512 + c4);
  }
  __syncthreads();
  for (int idx = tid; idx < 2048; idx += 256) {
    int ri = idx >> 9, c = idx & 511;
    const float* wt = taw + (i0 + ri) * 16;
    float a = 0.f;
    #pragma unroll
    for (int t = 0; t < 16; ++t) a = fmaf(wt[t], in[(4*ri + t)*512 + c], a);
    rm[ri*512 + c] = a;
  }
  __syncthreads();
  for (int idx = tid; idx < 512; idx += 256) {
    int ri = idx >> 7, ic = idx & 127;
    int j0 = taj[ic];
    float a = 0.f;
    #pragma unroll
    for (int t = 0; t < 16; ++t) {
      int j = min(511, max(0, j0 + t));
      a = fmaf(taw[ic*16 + t], rm[ri*512 + j], a);
    }
    hmrs[((size_t)bl*128 + i0 + ri)*128 + ic] = a;
  }
}

// ---------------- prior: sp(upsample(cond)) -> reversed fp8, 16B-chunk swizzled ----------------
__global__ void prior_rev_k(const float* __restrict__ cond, const int* __restrict__ tbj,
                            const float* __restrict__ tbw, unsigned char* __restrict__ pimg) {
  __shared__ float c64[HC_*HC_];
  int lk = blockIdx.x;
  const float* src = cond + (size_t)lk * HC_*HC_;
  for (int i = threadIdx.x; i < HC_*HC_; i += 256) c64[i] = src[i];
  __syncthreads();
  for (int t = threadIdx.x; t < 1024; t += 256) {
    int s = t >> 3, c16 = t & 7;
    int jy0 = tbj[s];
    float wy[4]; int jys[4];
    #pragma unroll
    for (int q = 0; q < 4; ++q) { wy[q] = tbw[s*4+q]; jys[q] = min(63, max(0, jy0 + q)); }
    unsigned w[4];
    #pragma unroll
    for (int q = 0; q < 4; ++q) {
      float vv[4];
      #pragma unroll
      for (int bq = 0; bq < 4; ++bq) {
        int jj = 16*c16 + 4*q + bq;
        int j = 127 - jj;
        int jx0 = tbj[j];
        float acc = 0.f;
        #pragma unroll
        for (int ty = 0; ty < 4; ++ty) {
          float r = 0.f;
          #pragma unroll
          for (int tx = 0; tx < 4; ++tx) {
            int jx = min(63, max(0, jx0 + tx));
            r = fmaf(tbw[j*4 + tx], c64[jys[ty]*64 + jx], r);
          }
          acc = fmaf(wy[ty], r, acc);
        }
        vv[bq] = sp(acc);
      }
      int wq = 0;
      wq = __builtin_amdgcn_cvt_pk_fp8_f32(vv[0], vv[1], wq, false);
      wq = __builtin_amdgcn_cvt_pk_fp8_f32(vv[2], vv[3], wq, true);
      w[q] = (unsigned)wq;
    }
    unsigned char* dst = pimg + (size_t)lk*16384 + s*128 + ((c16 ^ (s & 7)) << 4);
    *(uint4*)dst = make_uint4(w[0], w[1], w[2], w[3]);
  }
}

// ---------------- conv: implicit-Toeplitz MX-fp8 K=128 MFMA ----------------
// out[y][x] = sum_u sum_k Prev[y+64-u][k] * L[u][x-63+k]   (k = 127-t)
// Epilogue: contention-free e_all slice store (NO atomics; esum_k reduces over k).
__global__ __launch_bounds__(256, 3) void conv_mfma_k(
    const float* __restrict__ hmrs, const unsigned char* __restrict__ pimg,
    const float* __restrict__ bias, const int* __restrict__ vidx,
    const float* __restrict__ params, float* __restrict__ e_all) {
  extern __shared__ char lds[];
  char* Lb = lds;
  char* Pb = lds + PB_OFF;
  int blk = blockIdx.x;
  int b = blk / 296, lk = blk % 296;
  int tid = threadIdx.x;

  // zero L pads: per row dwords 0..15 and 48..63
  {
    unsigned* lz = (unsigned*)Lb;
    for (int i = tid; i < 4096; i += 256) {
      int row = i >> 5, q = i & 31;
      lz[row*64 + (q < 16 ? q : q + 32)] = 0u;
    }
  }
  // zero P pad rows 0..15, 144..159
  {
    unsigned* pz = (unsigned*)Pb;
    for (int i = tid; i < 1024; i += 256) {
      int row = i >> 5;
      pz[(row < 16 ? row : row + 128)*32 + (i & 31)] = 0u;
    }
  }
  // stage L = fp8(sp(sc*hmrs+sh))
  int vl = vidx[lk];
  float sc = params[2*vl], sh = params[2*vl + 1];
  const float4* likes4 = (const float4*)(hmrs + (size_t)(b * L_ + vl) * 16384);
  for (int i = tid; i < 1024; i += 256) {
    int u = i >> 3, ch = i & 7;
    int b4 = u * 32 + ch * 4;
    unsigned wds[4];
    #pragma unroll
    for (int q = 0; q < 4; ++q) {
      float4 v = likes4[b4 + q];
      int w = 0;
      w = __builtin_amdgcn_cvt_pk_fp8_f32(sp(fmaf(v.x, sc, sh)), sp(fmaf(v.y, sc, sh)), w, false);
      w = __builtin_amdgcn_cvt_pk_fp8_f32(sp(fmaf(v.z, sc, sh)), sp(fmaf(v.w, sc, sh)), w, true);
      wds[q] = (unsigned)w;
    }
    *(uint4*)(Lb + u*256 + 64 + ch*16) = make_uint4(wds[0], wds[1], wds[2], wds[3]);
  }
  // stage P data rows 16..143 (pre-swizzled)
  {
    const uint4* src = (const uint4*)(pimg + (size_t)lk * 16384);
    uint4* dst = (uint4*)(Pb + 16*128);
    for (int i = tid; i < 1024; i += 256) dst[i] = src[i];
  }
  __syncthreads();

  int wid = tid >> 6, lane = tid & 63;
  int wm = wid >> 1, wn = wid & 1;
  int l15 = lane & 15, kg = lane >> 4;
  int x0 = wn * 64, y_base = wm * 64;
  int bb = 1 + x0 + l15 + 32*kg;
  int bd0 = bb >> 2;
  int shiftB = (bb & 3) * 8;

  f32x4 acc[4][4];
  #pragma unroll
  for (int mt = 0; mt < 4; ++mt)
    #pragma unroll
    for (int nt = 0; nt < 4; ++nt)
      #pragma unroll
      for (int j = 0; j < 4; ++j) acc[mt][nt][j] = 0.f;

  int u_lo = wm ? 1 : 0;
  #pragma unroll 1
  for (int u = u_lo; u < 128; ++u) {
    const unsigned* Lr = (const unsigned*)(Lb + (u << 8));
    unsigned d[21];
    #pragma unroll
    for (int q = 0; q < 21; ++q) d[q] = Lr[bd0 + q];
    i32x8 Bf[4];
    #pragma unroll
    for (int nt = 0; nt < 4; ++nt)
      #pragma unroll
      for (int j = 0; j < 8; ++j)
        Bf[nt][j] = (int)(unsigned)((((unsigned long long)d[4*nt + j + 1] << 32) | d[4*nt + j]) >> shiftB);
    #pragma unroll
    for (int mt = 0; mt < 4; ++mt) {
      int yt = y_base + 16*mt;
      if (u < yt - 63 || u > yt + 79) continue;
      int r = yt + l15 + 80 - u;                       // storage row 1..158
      const char* pr = Pb + (r << 7);
      int m8 = r & 7;
      uint4 alo = *(const uint4*)(pr + (((2*kg)     ^ m8) << 4));
      uint4 ahi = *(const uint4*)(pr + (((2*kg + 1) ^ m8) << 4));
      i32x8 Af;
      Af[0] = (int)alo.x; Af[1] = (int)alo.y; Af[2] = (int)alo.z; Af[3] = (int)alo.w;
      Af[4] = (int)ahi.x; Af[5] = (int)ahi.y; Af[6] = (int)ahi.z; Af[7] = (int)ahi.w;
      #pragma unroll
      for (int nt = 0; nt < 4; ++nt)
        acc[mt][nt] = __builtin_amdgcn_mfma_scale_f32_16x16x128_f8f6f4(
            Af, Bf[nt], acc[mt][nt], 0, 0, 0, 0x7F7F7F7F, 0, 0x7F7F7F7F);
    }
  }

  // epilogue: log(conv + sp(bias) + delta) -> private e_all slice (streaming store)
  const float* bs = bias + (size_t)lk * 16384;
  float* eo = e_all + (size_t)(b * 296 + lk) * 16384;
  #pragma unroll
  for (int mt = 0; mt < 4; ++mt)
    #pragma unroll
    for (int nt = 0; nt < 4; ++nt) {
      int x = x0 + nt*16 + l15;
      int yb = y_base + mt*16 + kg*4;
      #pragma unroll
      for (int rg = 0; rg < 4; ++rg) {
        int y = yb + rg;
        float v = acc[mt][nt][rg] + sp(bs[y*128 + x]) + 1e-6f;
        eo[y*128 + x] = logf(v);
      }
    }
}

// ---------------- sum energies over k ----------------
__global__ void esum_k(const float* __restrict__ e_all, float* __restrict__ e128) {
  int bl = blockIdx.x; int tid = threadIdx.x;
  const float4* src = (const float4*)(e_all + (size_t)bl * 8 * 16384);
  float4* dst = (float4*)(e128 + (size_t)bl * 16384);
  for (int i = tid; i < 4096; i += 256) {
    float4 a = src[i];
    #pragma unroll
    for (int k = 1; k < 8; ++k) {
      float4 v = src[k * 4096 + i];
      a.x += v.x; a.y += v.y; a.z += v.z; a.w += v.w;
    }
    dst[i] = a;
  }
}

// ---------------- final: online softmax partials over 64-row segments ----------------
__global__ __launch_bounds__(256) void final_partial_k(
    const float* __restrict__ heat, const float* __restrict__ params,
    const float* __restrict__ e128, const int* __restrict__ tcj, const float* __restrict__ tcw,
    float* __restrict__ partials) {
  __shared__ float Elds[20 * 128];
  __shared__ float rm[256], rS[256], ry[256], rx[256];
  int blk = blockIdx.x;
  int bl = blk >> 3, seg = blk & 7;
  int l = bl % L_;
  int tid = threadIdx.x;
  float sc = params[2*l], sh = params[2*l+1];
  int y_lo = seg * 64;
  int r_lo = max(0, tcj[y_lo]);
  int r_hi = min(127, tcj[y_lo + 63] + 3);
  int nrows = r_hi - r_lo + 1;
  const float* E = e128 + (size_t)bl * 16384;
  for (int i = tid; i < nrows * 128; i += 256) Elds[i] = E[r_lo * 128 + i];
  __syncthreads();

  float wx[2][4]; int jx[2][4];
  #pragma unroll
  for (int xi = 0; xi < 2; ++xi) {
    int x = tid + xi * 256;
    int j0 = tcj[x];
    #pragma unroll
    for (int t = 0; t < 4; ++t) { wx[xi][t] = tcw[x*4 + t]; jx[xi][t] = min(127, max(0, j0 + t)); }
  }

  float m = -1e30f, S = 0.f, Sy = 0.f, Sx = 0.f;
  for (int y = y_lo; y < y_lo + 64; ++y) {
    int jy0 = tcj[y];
    float wy[4]; int jyr[4];
    #pragma unroll
    for (int t = 0; t < 4; ++t) { wy[t] = tcw[y*4 + t]; jyr[t] = min(127, max(0, jy0 + t)) - r_lo; }
    #pragma unroll
    for (int xi = 0; xi < 2; ++xi) {
      int x = tid + xi * 256;
      float a = 0.f;
      #pragma unroll
      for (int t = 0; t < 4; ++t) {
        const float* Er = Elds + jyr[t] * 128;
        float rrow = wx[xi][0]*Er[jx[xi][0]] + wx[xi][1]*Er[jx[xi][1]]
                   + wx[xi][2]*Er[jx[xi][2]] + wx[xi][3]*Er[jx[xi][3]];
        a = fmaf(wy[t], rrow, a);
      }
      float hm = fmaf(heat[(size_t)bl * 262144 + y * 512 + x], sc, sh);
      float e = a + logf(sp(hm) + 1e-6f);
      if (e > m) {
        float f = expf(m - e);
        S *= f; Sy *= f; Sx *= f; m = e;
      }
      float w = expf(e - m);
      S += w; Sy = fmaf(w, (float)y, Sy); Sx = fmaf(w, (float)x, Sx);
    }
  }
  rm[tid] = m; rS[tid] = S; ry[tid] = Sy; rx[tid] = Sx; __syncthreads();
  for (int o = 128; o > 0; o >>= 1) {
    if (tid < o) {
      float ma = rm[tid], mb = rm[tid + o];
      float M = fmaxf(ma, mb);
      float fa = expf(ma - M), fb = expf(mb - M);
      rS[tid] = rS[tid]*fa + rS[tid+o]*fb;
      ry[tid] = ry[tid]*fa + ry[tid+o]*fb;
      rx[tid] = rx[tid]*fa + rx[tid+o]*fb;
      rm[tid] = M;
    }
    __syncthreads();
  }
  if (tid == 0) {
    float* p = partials + (size_t)blk * 4;
    p[0] = rm[0]; p[1] = rS[0]; p[2] = ry[0]; p[3] = rx[0];
  }
}

__global__ void final_combine_k(const float* __restrict__ partials, float* __restrict__ out) {
  int bl = blockIdx.x;
  if (threadIdx.x != 0) return;
  float M = -1e30f, S = 0.f, Sy = 0.f, Sx = 0.f;
  for (int i = 0; i < 8; ++i) {
    const float* p = partials + (size_t)(bl * 8 + i) * 4;
    float m2 = p[0], s2 = p[1], sy2 = p[2], sx2 = p[3];
    float Mn = fmaxf(M, m2);
    float fa = expf(M - Mn), fb = expf(m2 - Mn);
    S = S*fa + s2*fb; Sy = Sy*fa + sy2*fb; Sx = Sx*fa + sx2*fb; M = Mn;
  }
  out[bl*3 + 0] = 1.f;
  out[bl*3 + 1] = Sy / S;
  out[bl*3 + 2] = Sx / S;
}

extern "C" void kernel_launch(void* const* d_in, const int* in_sizes, int n_in,
                              void* d_out, int out_size, void* d_ws, size_t ws_size,
                              hipStream_t stream) {
  const float* heat  = (const float*)d_in[0];
  const float* cond  = (const float*)d_in[1];
  const float* bias  = (const float*)d_in[2];
  const float* gamma = (const float*)d_in[3];
  const float* beta  = (const float*)d_in[4];
  const int*   vidx  = (const int*)d_in[5];
  float* out = (float*)d_out;
  char* ws = (char*)d_ws;

  float* sums   = (float*)(ws + OFF_SUMS);
  float* params = (float*)(ws + OFF_PARAMS);
  int*   taj = (int*)(ws + OFF_TAJ);   float* taw = (float*)(ws + OFF_TAW);
  int*   tbj = (int*)(ws + OFF_TBJ);   float* tbw = (float*)(ws + OFF_TBW);
  int*   tcj = (int*)(ws + OFF_TCJ);   float* tcw = (float*)(ws + OFF_TCW);
  float* part  = (float*)(ws + OFF_PART);
  float* hmrs  = (float*)(ws + OFF_HMRS);
  unsigned char* pimg = (unsigned char*)(ws + OFF_PIMG);
  float* e_all = (float*)(ws + OFF_EALL);
  float* e128  = (float*)(ws + OFF_E128);

  hipFuncSetAttribute((const void*)conv_mfma_k,
                      hipFuncAttributeMaxDynamicSharedMemorySize, CONV_LDS);
  hipFuncSetAttribute((const void*)down_fused_k,
                      hipFuncAttributeMaxDynamicSharedMemorySize, 32*512*4);

  hipMemsetAsync(sums, 0, 2 * L_ * sizeof(float), stream);

  bn_partial_k<<<L_ * 16, 256, 0, stream>>>(heat, sums);
  tables_k<<<1, 512, 0, stream>>>(taj, taw, tbj, tbw, tcj, tcw, sums, gamma, beta, params);
  down_fused_k<<<74 * 32, 256, 32*512*4, stream>>>(heat, taj, taw, hmrs);
  prior_rev_k<<<L_ * K_, 256, 0, stream>>>(cond, tbj, tbw, pimg);
  conv_mfma_k<<<2 * L_ * K_, 256, CONV_LDS, stream>>>(hmrs, pimg, bias, vidx, params, e_all);
  esum_k<<<74, 256, 0, stream>>>(e_all, e128);
  final_partial_k<<<74 * 8, 256, 0, stream>>>(heat, params, e128, tcj, tcw, part);
  final_combine_k<<<74, 64, 0, stream>>>(part, out);
}